// Round 1
// baseline (408.053 us; speedup 1.0000x reference)
//
#include <hip/hip_runtime.h>

// Problem constants (from reference setup_inputs)
constexpr int B  = 16;
constexpr int C  = 3;
constexpr int H  = 768;
constexpr int W  = 1024;
constexpr int HW = H * W;

// Fused: bilinear backwarp(ten_second, flow) -> |ten_first - warped| -> mean over C -> * alpha
// Math note: the reference's grid construction collapses to
//   ix = x + flow_x * W/(W-1),  iy = y + flow_y * H/(H-1)
// Corner validity uses UNclipped integer coords; invalid corners contribute 0.
__global__ __launch_bounds__(256) void warp_l1_mean_kernel(
    const float* __restrict__ first,
    const float* __restrict__ second,
    const float* __restrict__ flow,
    const float* __restrict__ alpha,
    float* __restrict__ out)
{
    const int gid = blockIdx.x * blockDim.x + threadIdx.x;  // b*HW + y*W + x
    if (gid >= B * HW) return;

    const int b = gid / HW;
    const int p = gid - b * HW;     // y*W + x
    const int y = p / W;
    const int x = p - y * W;

    const float* fl = flow + (size_t)b * 2 * HW;
    const float fx = fl[p];
    const float fy = fl[HW + p];

    const float ix = (float)x + fx * ((float)W / (float)(W - 1));
    const float iy = (float)y + fy * ((float)H / (float)(H - 1));

    const float x0f = floorf(ix);
    const float y0f = floorf(iy);
    const float wx1 = ix - x0f;
    const float wy1 = iy - y0f;
    const float wx0 = 1.0f - wx1;
    const float wy0 = 1.0f - wy1;

    const int x0 = (int)x0f;
    const int y0 = (int)y0f;
    const int x1 = x0 + 1;
    const int y1 = y0 + 1;

    const bool vx0 = (x0 >= 0) && (x0 <= W - 1);
    const bool vx1 = (x1 >= 0) && (x1 <= W - 1);
    const bool vy0 = (y0 >= 0) && (y0 <= H - 1);
    const bool vy1 = (y1 >= 0) && (y1 <= H - 1);

    const int cx0 = min(max(x0, 0), W - 1);
    const int cx1 = min(max(x1, 0), W - 1);
    const int cy0 = min(max(y0, 0), H - 1);
    const int cy1 = min(max(y1, 0), H - 1);

    const float w00 = wy0 * wx0 * ((vx0 && vy0) ? 1.0f : 0.0f);
    const float w01 = wy0 * wx1 * ((vx1 && vy0) ? 1.0f : 0.0f);
    const float w10 = wy1 * wx0 * ((vx0 && vy1) ? 1.0f : 0.0f);
    const float w11 = wy1 * wx1 * ((vx1 && vy1) ? 1.0f : 0.0f);

    const int i00 = cy0 * W + cx0;
    const int i01 = cy0 * W + cx1;
    const int i10 = cy1 * W + cx0;
    const int i11 = cy1 * W + cx1;

    const float* sec = second + (size_t)b * C * HW;
    const float* fst = first  + (size_t)b * C * HW;
    const float a = alpha[0];

    float acc = 0.0f;
#pragma unroll
    for (int c = 0; c < C; ++c) {
        const float* s = sec + c * HW;
        const float warped = w00 * s[i00] + w01 * s[i01]
                           + w10 * s[i10] + w11 * s[i11];
        acc += fabsf(fst[c * HW + p] - warped);
    }

    out[gid] = a * (acc * (1.0f / 3.0f));
}

extern "C" void kernel_launch(void* const* d_in, const int* in_sizes, int n_in,
                              void* d_out, int out_size, void* d_ws, size_t ws_size,
                              hipStream_t stream) {
    const float* first  = (const float*)d_in[0];
    const float* second = (const float*)d_in[1];
    const float* flow   = (const float*)d_in[2];
    const float* alpha  = (const float*)d_in[3];
    float* out = (float*)d_out;

    const int total = B * HW;                 // 12,582,912
    const int block = 256;
    const int grid  = (total + block - 1) / block;  // 49,152

    warp_l1_mean_kernel<<<grid, block, 0, stream>>>(first, second, flow, alpha, out);
}